// Round 14
// baseline (237.421 us; speedup 1.0000x reference)
//
#include <hip/hip_runtime.h>

// Problem: B=4, N=2048, C=768, H=12, D=64. I/O f32; internals bf16 MFMA + f32 acc.
// Pipeline: prep(LN + both weight transposes, FUSED) -> QKV GEMM -> flash attn ->
//           out-proj GEMM (+bias +residual).
// R25: gemm_out grid-balance fix. R24 showed boundaries cost ~1us each (fusion
//   gained 2us, not 10) -> remaining budget is in-kernel. gemm_out was the only
//   kernel at 1.5 blocks/CU (384 blocks): half the CUs run 2 sequential blocks.
//   Split M: 64x128 tiles -> grid 768 = exactly 3 blocks/CU, 48KB LDS so all 3
//   resident concurrently (no sequential rounds). Same 2-phase discipline
//   (24 subtiles, 6 gll16/wave/stage, vmcnt(6) steady). qkv/attn/prep = R24
//   (qkv: 2-phase ceiling proven R20/R21/R23; attn: 88% LDS-port structural;
//   R17/R18/R22 K/V-in-regs arc closed).

typedef __bf16 bf16x8 __attribute__((ext_vector_type(8)));
typedef float  f32x4  __attribute__((ext_vector_type(4)));
typedef unsigned int u32x4 __attribute__((ext_vector_type(4)));

#define MFMA16(a,b,c) __builtin_amdgcn_mfma_f32_16x16x32_bf16((a),(b),(c),0,0,0)

__device__ inline f32x4 zero4() { f32x4 z = {0.f,0.f,0.f,0.f}; return z; }

// async global->LDS, 16B per lane; lds dest is wave-uniform base + lane*16
__device__ inline void gll16(const __bf16* g, __bf16* l) {
  __builtin_amdgcn_global_load_lds((const __attribute__((address_space(1))) unsigned int*)g,
                                   (__attribute__((address_space(3))) unsigned int*)l,
                                   16, 0, 0);
}

// pack two f32 -> bf16x2 (RNE); no builtin on gfx950, inline asm per guide
__device__ inline unsigned cvt_pk_bf16(float lo, float hi) {
  unsigned r;
  asm("v_cvt_pk_bf16_f32 %0, %1, %2" : "=v"(r) : "v"(lo), "v"(hi));
  return r;
}
// a[32:63] <-> b[0:31]
__device__ inline void permlane32_swap(unsigned &a, unsigned &b) {
  asm("v_permlane32_swap_b32 %0, %1" : "+v"(a), "+v"(b));
}
// a[16:31]<->b[0:15], a[48:63]<->b[32:47]
__device__ inline void permlane16_swap(unsigned &a, unsigned &b) {
  asm("v_permlane16_swap_b32 %0, %1" : "+v"(a), "+v"(b));
}

// ---------------- Fused prep: LN (blocks 0..8191) + transpose wqkv (next 1728)
// ---------------- + transpose wout (next 576). One launch instead of three.
__global__ __launch_bounds__(256) void prep_kernel(const float* __restrict__ x,
                                                   const float* __restrict__ g,
                                                   const float* __restrict__ bt,
                                                   __bf16* __restrict__ xn,
                                                   const float* __restrict__ wqkv,
                                                   __bf16* __restrict__ wqkvT,
                                                   const float* __restrict__ wout,
                                                   __bf16* __restrict__ woutT) {
  __shared__ float t[32][33];      // transpose tile (ln uses first 8 floats)
  const int bid = blockIdx.x;
  const int tid = threadIdx.x;
  if (bid < 8192) {
    // ---- LayerNorm row ----
    const int row = bid;
    const float* xr = x + (size_t)row * 768;
    float v[3]; float s = 0.f, ss = 0.f;
    #pragma unroll
    for (int i = 0; i < 3; ++i) { float f = xr[tid + 256*i]; v[i] = f; s += f; ss += f*f; }
    #pragma unroll
    for (int m = 32; m >= 1; m >>= 1) { s += __shfl_xor(s, m, 64); ss += __shfl_xor(ss, m, 64); }
    float* red = &t[0][0];
    const int wave = tid >> 6;
    if ((tid & 63) == 0) { red[wave] = s; red[4 + wave] = ss; }
    __syncthreads();
    s  = red[0] + red[1] + red[2] + red[3];
    ss = red[4] + red[5] + red[6] + red[7];
    const float mu  = s * (1.f/768.f);
    const float var = ss * (1.f/768.f) - mu*mu;
    const float inv = rsqrtf(var + 1e-5f);
    __bf16* xo = xn + (size_t)row * 768;
    #pragma unroll
    for (int i = 0; i < 3; ++i) {
      const int c0 = tid + 256*i;
      xo[c0] = (__bf16)((v[i] - mu) * inv * g[c0] + bt[c0]);
    }
  } else {
    // ---- 32x32 tiled transpose + f32->bf16 ----
    const float* in; __bf16* out; int R, C, bx, by;
    if (bid < 8192 + 1728) {
      const int tt = bid - 8192;
      in = wqkv; out = wqkvT; R = 768; C = 2304;
      bx = tt % 72; by = tt / 72;
    } else {
      const int tt = bid - (8192 + 1728);
      in = wout; out = woutT; R = 768; C = 768;
      bx = tt % 24; by = tt / 24;
    }
    const int tx = tid & 31, ty = tid >> 5;
    const int c0 = bx * 32, r0 = by * 32;
    #pragma unroll
    for (int p = 0; p < 4; ++p) t[ty + 8*p][tx] = in[(size_t)(r0 + ty + 8*p) * C + c0 + tx];
    __syncthreads();
    #pragma unroll
    for (int p = 0; p < 4; ++p) out[(size_t)(c0 + ty + 8*p) * R + r0 + tx] = (__bf16)t[tx][ty + 8*p];
  }
}

// ---------------- GEMM mainloop BK=64, double-buffered: C[128x128] = A @ BT^T (bf16) ----
// LDS per buffer: 16 subtiles of 16x32 per operand (st = rowblk*2 + khalf, 1KB each);
// two buffers per operand (64KB total). Wave stages 4 A + 4 B subtiles (8 gll16).
// Steady state: compute buf[t&1] while stage(t+1)'s 8 loads are in flight
// (vmcnt(8) at top, never 0 mid-loop); stage(t+2) issued after the read-done barrier.
template<int KDIM>
__device__ inline void gemm_mainloop(const __bf16* __restrict__ A, const __bf16* __restrict__ BT,
                                     int bm, int bn, int wave, int lane,
                                     f32x4 acc[4][4], __bf16* Asm, __bf16* Bsm) {
  const int wm = wave >> 1, wn = wave & 1;
  const int lr = lane & 15, lk = lane >> 4;
  constexpr int NIT = KDIM / 64;
  auto stage = [&](int t) {
    const int k0 = t * 64;
    __bf16* Ad = Asm + (t & 1) * 8192;
    __bf16* Bd = Bsm + (t & 1) * 8192;
    #pragma unroll
    for (int s2 = 0; s2 < 4; ++s2) {
      const int st = wave * 4 + s2;
      const int rb = st >> 1, kh = st & 1;
      gll16(A  + (size_t)(bm + rb*16 + lr) * KDIM + k0 + kh*32 + lk*8, Ad + st*512);
      gll16(BT + (size_t)(bn + rb*16 + lr) * KDIM + k0 + kh*32 + lk*8, Bd + st*512);
    }
  };
  stage(0);
  stage(1);
  for (int t = 0; t < NIT; ++t) {
    if (t + 1 < NIT) asm volatile("s_waitcnt vmcnt(8)" ::: "memory");
    else             asm volatile("s_waitcnt vmcnt(0)" ::: "memory");
    asm volatile("s_barrier" ::: "memory");      // all waves' stage(t) visible
    const __bf16* Ab = Asm + (t & 1) * 8192;
    const __bf16* Bb = Bsm + (t & 1) * 8192;
    #pragma unroll
    for (int ks = 0; ks < 2; ++ks) {
      bf16x8 a[4], b[4];
      #pragma unroll
      for (int mt = 0; mt < 4; ++mt) a[mt] = *(const bf16x8*)(Ab + ((wm*4+mt)*2+ks)*512 + lane*8);
      #pragma unroll
      for (int nt = 0; nt < 4; ++nt) b[nt] = *(const bf16x8*)(Bb + ((wn*4+nt)*2+ks)*512 + lane*8);
      __builtin_amdgcn_s_setprio(1);
      #pragma unroll
      for (int mt = 0; mt < 4; ++mt)
        #pragma unroll
        for (int nt = 0; nt < 4; ++nt)
          acc[mt][nt] = MFMA16(a[mt], b[nt], acc[mt][nt]);
      __builtin_amdgcn_s_setprio(0);
    }
    asm volatile("s_barrier" ::: "memory");      // all waves done reading buf[t&1]
    if (t + 2 < NIT) stage(t + 2);               // overwrite buf[t&1] for t+2
  }
}

// ---------------- QKV GEMM: xn[8192,768] @ wqkvT[2304,768]^T ----------------
// Q/K blocks (bn<1536) store direct. V blocks (bn>=1536) transpose the 128x128 acc
// tile in LDS (pad-66) and store V^T [B,H,D,N] coalesced. Transpose tile aliases staging.
// Grid: 1152 linear blocks, XCD-swizzled (144/XCD = 8 bm-rows x 18 bn-cols ->
// B panel 3.5MB ~resident in its 4MB L2). [R20/R21/R23: BK=32, 3-stage, and
// 8-phase 256^2 all ~67us -- 2-phase 128^2 is the practical optimum here.]
__global__ __launch_bounds__(256) void gemm_qkv_kernel(const __bf16* __restrict__ A,
                                                       const __bf16* __restrict__ BT,
                                                       __bf16* __restrict__ q,
                                                       __bf16* __restrict__ k,
                                                       __bf16* __restrict__ vt) {
  __shared__ __align__(16) __bf16 smem[4*8192];   // A dbuf + B dbuf (64KB); aliased transpose tile
  __bf16* Asm = smem;
  __bf16* Bsm = smem + 2*8192;
  const int lane = threadIdx.x & 63, wave = threadIdx.x >> 6;
  const int wg = ((int)blockIdx.x & 7) * 144 + ((int)blockIdx.x >> 3);
  const int bm = (wg / 18) * 128, bn = (wg % 18) * 128;
  f32x4 acc[4][4];
  #pragma unroll
  for (int i = 0; i < 4; ++i)
    #pragma unroll
    for (int j = 0; j < 4; ++j) acc[i][j] = zero4();
  gemm_mainloop<768>(A, BT, bm, bn, wave, lane, acc, Asm, Bsm);
  const int wm = wave >> 1, wn = wave & 1;
  const int quad = lane >> 4, c = lane & 15;
  if (bn < 1536) {
    // Q pre-scale: 1/sqrt(64) * log2(e) so attention does p = exp2(score) natively
    const float qscale = 0.125f * 1.44269504088896f;
    #pragma unroll
    for (int mt = 0; mt < 4; ++mt)
      #pragma unroll
      for (int nt = 0; nt < 4; ++nt) {
        const int col = bn + wn*64 + nt*16 + c;           // 0..1535
        const int which = col >= 768 ? 1 : 0;
        const int within = col - which*768;
        const int h = within >> 6, d = within & 63;
        #pragma unroll
        for (int r = 0; r < 4; ++r) {
          const int row = bm + wm*64 + mt*16 + quad*4 + r; // 0..8191
          const int b = row >> 11, n = row & 2047;
          const float vv = acc[mt][nt][r];
          const size_t idx = ((size_t)(b*12 + h) * 2048 + n) * 64 + d;  // [B,H,N,D]
          if (which == 0) q[idx] = (__bf16)(vv * qscale);
          else            k[idx] = (__bf16)vv;
        }
      }
  } else {
    __syncthreads();   // staging buffers dead; reuse as transpose tile
    #pragma unroll
    for (int mt = 0; mt < 4; ++mt)
      #pragma unroll
      for (int nt = 0; nt < 4; ++nt) {
        const int lcol = wn*64 + nt*16 + c;
        #pragma unroll
        for (int r = 0; r < 4; ++r) {
          const int lrow = wm*64 + mt*16 + quad*4 + r;
          smem[lrow*66 + lcol] = (__bf16)acc[mt][nt][r];
        }
      }
    __syncthreads();
    const int b = bm >> 11, n0 = bm & 2047;
    const int vo = bn - 1536;                // 0..639 (V-region col offset)
    const int n = threadIdx.x & 127;
    const int csel = threadIdx.x >> 7;
    #pragma unroll
    for (int pass = 0; pass < 64; ++pass) {
      const int lc = pass*2 + csel;          // 0..127
      const int gcol = vo + lc;              // 0..767
      const int h = gcol >> 6, d = gcol & 63;
      vt[((size_t)(b*12 + h)*64 + d)*2048 + n0 + n] = smem[n*66 + lc];
    }
  }
}

// ---------------- Out-proj GEMM 64x128 tiles: o[8192,768] @ woutT[768,768]^T ----------------
// + f32 bias + f32 residual. R25: 768 blocks = exactly 3 blocks/CU (48KB LDS, all
// resident) vs R24's 384 at 1.5/CU imbalance. 24 subtiles/stage (A 8 + B 16),
// 6 gll16/wave/stage, steady vmcnt(6). Wave w owns 64 rows x 32-col strip
// (acc[4][2]). XCD swizzle: 96/XCD = 16 bm x 6 bn contiguous.
__global__ __launch_bounds__(256) void gemm_out_kernel(const __bf16* __restrict__ A,
                                                       const __bf16* __restrict__ BT,
                                                       const float* __restrict__ bias,
                                                       const float* __restrict__ resid,
                                                       float* __restrict__ out) {
  __shared__ __align__(16) __bf16 Asm[2*4096];   // 2 buf x 8 subtiles (16KB)
  __shared__ __align__(16) __bf16 Bsm[2*8192];   // 2 buf x 16 subtiles (32KB)
  const int lane = threadIdx.x & 63, wave = threadIdx.x >> 6;
  const int lr = lane & 15, lk = lane >> 4;
  const int wg = ((int)blockIdx.x & 7) * 96 + ((int)blockIdx.x >> 3);
  const int bm = (wg / 6) * 64, bn = (wg % 6) * 128;
  constexpr int KD = 768;
  constexpr int NIT = 12;
  auto stage = [&](int t) {
    const int k0 = t * 64;
    __bf16* Ad = Asm + (t & 1) * 4096;
    __bf16* Bd = Bsm + (t & 1) * 8192;
    #pragma unroll
    for (int s = 0; s < 6; ++s) {
      const int idx = wave * 6 + s;              // 0..23
      if (idx < 8) {                             // A subtile: 4 rowblocks x 2 khalves
        const int rb = idx >> 1, kh = idx & 1;
        gll16(A + (size_t)(bm + rb*16 + lr) * KD + k0 + kh*32 + lk*8, Ad + idx*512);
      } else {                                   // B subtile: 8 rowblocks x 2 khalves
        const int j = idx - 8;
        const int rb = j >> 1, kh = j & 1;
        gll16(BT + (size_t)(bn + rb*16 + lr) * KD + k0 + kh*32 + lk*8, Bd + j*512);
      }
    }
  };
  f32x4 acc[4][2];
  #pragma unroll
  for (int i = 0; i < 4; ++i)
    #pragma unroll
    for (int j = 0; j < 2; ++j) acc[i][j] = zero4();
  stage(0);
  stage(1);
  for (int t = 0; t < NIT; ++t) {
    if (t + 1 < NIT) asm volatile("s_waitcnt vmcnt(6)" ::: "memory");
    else             asm volatile("s_waitcnt vmcnt(0)" ::: "memory");
    asm volatile("s_barrier" ::: "memory");      // all waves' stage(t) visible
    const __bf16* Ab = Asm + (t & 1) * 4096;
    const __bf16* Bb = Bsm + (t & 1) * 8192;
    #pragma unroll
    for (int ks = 0; ks < 2; ++ks) {
      bf16x8 a[4], b[2];
      #pragma unroll
      for (int mt = 0; mt < 4; ++mt) a[mt] = *(const bf16x8*)(Ab + (mt*2+ks)*512 + lane*8);
      #pragma unroll
      for (int nt = 0; nt < 2; ++nt) b[nt] = *(const bf16x8*)(Bb + ((wave*2+nt)*2+ks)*512 + lane*8);
      __builtin_amdgcn_s_setprio(1);
      #pragma unroll
      for (int mt = 0; mt < 4; ++mt)
        #pragma unroll
        for (int nt = 0; nt < 2; ++nt)
          acc[mt][nt] = MFMA16(a[mt], b[nt], acc[mt][nt]);
      __builtin_amdgcn_s_setprio(0);
    }
    asm volatile("s_barrier" ::: "memory");      // all waves done reading buf[t&1]
    if (t + 2 < NIT) stage(t + 2);               // overwrite buf[t&1] for t+2
  }
  const int quad = lane >> 4, c = lane & 15;
  #pragma unroll
  for (int mt = 0; mt < 4; ++mt)
    #pragma unroll
    for (int nt = 0; nt < 2; ++nt) {
      const int col = bn + wave*32 + nt*16 + c;
      #pragma unroll
      for (int r = 0; r < 4; ++r) {
        const int row = bm + mt*16 + quad*4 + r;
        out[(size_t)row*768 + col] = acc[mt][nt][r] + bias[col] + resid[(size_t)row*768 + col];
      }
    }
}

// ---------------- Flash attention: 1 block = (b,h) x 128 q-rows; 8 waves x 16 rows ----
// R19/R14 structure (settled optimum: ~67-69us at ~88% LDS-port util): swapped QK^T
// (S^T = mfma(K,Q), lane's S regs are its own q-row = lane&15); p = exp2(s)
// in-register; P->bf16 PV A-frag via cvt_pk + permlane32/16_swap. K/V double-
// buffered block-shared DMA (2 gll16/wave/stage), 32KB LDS, vmcnt(2) steady.
// Row-sum via ones-operand MFMA. [R17/R18/R22: any K/V-to-registers variant
// spills or serializes -- do not reopen.]
__global__ __launch_bounds__(512, 6) void attn_kernel(const __bf16* __restrict__ q,
                                                      const __bf16* __restrict__ k,
                                                      const __bf16* __restrict__ vt,
                                                      __bf16* __restrict__ o) {
  const int xcd = blockIdx.x & 7, i = blockIdx.x >> 3;
  const int bh = xcd * 6 + (i >> 4);   // 0..47
  const int qt = i & 15;               // 16 q-tiles of 128 rows
  const int lane = threadIdx.x & 63, wave = threadIdx.x >> 6;   // wave 0..7
  const int c = lane & 15, quad = lane >> 4;
  const int lr = lane & 15, lk = lane >> 4;
  const int q0 = qt*128 + wave*16;

  const __bf16* qb = q  + ((size_t)bh*2048 + q0) * 64;
  const __bf16* kb = k  + (size_t)bh * 2048 * 64;
  const __bf16* vb = vt + (size_t)bh * 64 * 2048;

  __shared__ __align__(16) __bf16 Ksm[2][4096];
  __shared__ __align__(16) __bf16 Vsm[2][4096];

  bf16x8 aq[2];
  aq[0] = *(const bf16x8*)(qb + (size_t)c*64 + quad*8);
  aq[1] = *(const bf16x8*)(qb + (size_t)c*64 + 32 + quad*8);

  const __bf16 one = (__bf16)1.0f;
  bf16x8 vones;
  #pragma unroll
  for (int j = 0; j < 8; ++j) vones[j] = one;

  f32x4 od[4];
  f32x4 clacc = zero4();
  #pragma unroll
  for (int r = 0; r < 4; ++r) od[r] = zero4();

  auto stage = [&](int it) {
    const int kt = it * 64;
    __bf16* Ks = Ksm[it & 1];
    __bf16* Vs = Vsm[it & 1];
    gll16(kb + (size_t)(kt + (wave>>1)*16 + lr) * 64 + (wave&1)*32 + lk*8,  Ks + wave*512);
    gll16(vb + (size_t)((wave>>1)*16 + lr) * 2048 + kt + (wave&1)*32 + lk*8, Vs + wave*512);
  };

  stage(0);
  stage(1);

  for (int it = 0; it < 32; ++it) {
    const __bf16* Ks = Ksm[it & 1];
    const __bf16* Vs = Vsm[it & 1];
    if (it < 31) asm volatile("s_waitcnt vmcnt(2)" ::: "memory");
    else         asm volatile("s_waitcnt vmcnt(0)" ::: "memory");
    asm volatile("s_barrier" ::: "memory");
    #pragma unroll
    for (int ch = 0; ch < 2; ++ch) {
      unsigned pk[2][2];
      #pragma unroll
      for (int t2 = 0; t2 < 2; ++t2) {
        const int t = ch*2 + t2;
        const bf16x8 ka0 = *(const bf16x8*)(Ks + (t*2+0)*512 + lane*8);
        const bf16x8 ka1 = *(const bf16x8*)(Ks + (t*2+1)*512 + lane*8);
        f32x4 z = zero4();
        __builtin_amdgcn_s_setprio(1);
        z = MFMA16(ka0, aq[0], z);
        z = MFMA16(ka1, aq[1], z);
        __builtin_amdgcn_s_setprio(0);
        const float p0 = __builtin_amdgcn_exp2f(z[0]);
        const float p1 = __builtin_amdgcn_exp2f(z[1]);
        const float p2 = __builtin_amdgcn_exp2f(z[2]);
        const float p3 = __builtin_amdgcn_exp2f(z[3]);
        pk[t2][0] = cvt_pk_bf16(p0, p1);
        pk[t2][1] = cvt_pk_bf16(p2, p3);
      }
      unsigned s0 = pk[0][0], s2 = pk[1][0];
      permlane32_swap(s0, s2);
      permlane16_swap(s0, s2);
      unsigned s1 = pk[0][1], s3 = pk[1][1];
      permlane32_swap(s1, s3);
      permlane16_swap(s1, s3);
      u32x4 w4; w4.x = s0; w4.y = s1; w4.z = s2; w4.w = s3;
      const bf16x8 pa = __builtin_bit_cast(bf16x8, w4);
      __builtin_amdgcn_s_setprio(1);
      #pragma unroll
      for (int dt = 0; dt < 4; ++dt) {
        const bf16x8 bv = *(const bf16x8*)(Vs + (dt*2+ch)*512 + lane*8);
        od[dt] = MFMA16(pa, bv, od[dt]);
      }
      clacc = MFMA16(pa, vones, clacc);
      __builtin_amdgcn_s_setprio(0);
    }
    asm volatile("s_barrier" ::: "memory");
    if (it + 2 < 32) stage(it + 2);
  }
  const int b = bh / 12, h = bh % 12;
  float rl[4];
  #pragma unroll
  for (int r = 0; r < 4; ++r) rl[r] = 1.f / clacc[r];
  #pragma unroll
  for (int dt = 0; dt < 4; ++dt)
    #pragma unroll
    for (int r = 0; r < 4; ++r) {
      const int n = q0 + quad*4 + r;
      const int col = h*64 + dt*16 + c;
      o[((size_t)b*2048 + n)*768 + col] = (__bf16)(od[dt][r] * rl[r]);
    }
}

extern "C" void kernel_launch(void* const* d_in, const int* in_sizes, int n_in,
                              void* d_out, int out_size, void* d_ws, size_t ws_size,
                              hipStream_t stream) {
  const float* img   = (const float*)d_in[0];
  const float* gamma = (const float*)d_in[1];
  const float* beta  = (const float*)d_in[2];
  const float* wqkv  = (const float*)d_in[3];
  const float* wout  = (const float*)d_in[4];
  const float* bout  = (const float*)d_in[5];
  float* out = (float*)d_out;

  __bf16* ws = (__bf16*)d_ws;
  size_t off = 0;
  __bf16* xn    = ws + off; off += (size_t)8192*768;   // LN output (bf16)
  __bf16* wqkvT = ws + off; off += (size_t)2304*768;   // w_qkv^T (bf16)
  __bf16* woutT = ws + off; off += (size_t)768*768;    // w_out^T (bf16)
  __bf16* qs    = ws + off; off += (size_t)48*2048*64; // Q*0.125*log2e [B,H,N,D]
  __bf16* ks    = ws + off; off += (size_t)48*2048*64; // K     [B,H,N,D]
  __bf16* vts   = ws + off; off += (size_t)48*64*2048; // V^T   [B,H,D,N]
  __bf16* os    = ws + off; off += (size_t)8192*768;   // attn out [B,N,C]

  // fused prep: 8192 LN rows + 1728 wqkv-transpose tiles + 576 wout-transpose tiles
  prep_kernel<<<8192 + 1728 + 576, 256, 0, stream>>>(img, gamma, beta, xn,
                                                     wqkv, wqkvT, wout, woutT);
  gemm_qkv_kernel<<<1152, 256, 0, stream>>>(xn, wqkvT, qs, ks, vts);
  attn_kernel<<<768, 512, 0, stream>>>(qs, ks, vts, os);
  gemm_out_kernel<<<768, 256, 0, stream>>>(os, woutT, bout, img, out);
}